// Round 8
// baseline (433.762 us; speedup 1.0000x reference)
//
#include <hip/hip_runtime.h>
#include <math.h>

#define NQ     512
#define DD     27
#define DP     28               // padded row: 27 scaled dims + (-0.5*||f||^2)
#define NC     10
#define KK     3
#define NTHR   256
#define NSLICE 256              // feature slices
#define NGRP   8                // query groups of 64 (1 query per lane)
#define NBLK   (NSLICE*NGRP)    // 2048 blocks = 8 blocks/CU, fully resident
#define NCAND  (NSLICE*3)       // 768 candidates per query

static __device__ __forceinline__ unsigned fbits(float x){ return __float_as_uint(x); }

// K1: scale[d] = max |features[:,d]| (proven r2-r6).
__global__ void k_scale(const float* __restrict__ feats, unsigned* __restrict__ scale_bits,
                        int total, int total_f4) {
  __shared__ unsigned smax[DD];
  int t = threadIdx.x;
  if (t < DD) smax[t] = 0u;
  __syncthreads();
  int gid = blockIdx.x * blockDim.x + t;
  int stride = gridDim.x * blockDim.x;       // 864*256 = 221184 f4 ≡ 0 mod 27
  const float4* f4 = (const float4*)feats;
  float m0=0.f, m1=0.f, m2=0.f, m3=0.f;
  for (int i = gid; i < total_f4; i += stride) {
    float4 v = f4[i];
    m0 = fmaxf(m0, fabsf(v.x));
    m1 = fmaxf(m1, fabsf(v.y));
    m2 = fmaxf(m2, fabsf(v.z));
    m3 = fmaxf(m3, fabsf(v.w));
  }
  int d0 = (4*gid) % DD;
  atomicMax(&smax[d0],          fbits(m0));
  atomicMax(&smax[(d0+1)%DD],   fbits(m1));
  atomicMax(&smax[(d0+2)%DD],   fbits(m2));
  atomicMax(&smax[(d0+3)%DD],   fbits(m3));
  if (gid == 0) {
    for (int i = total_f4*4; i < total; ++i)
      atomicMax(&scale_bits[i % DD], fbits(fabsf(feats[i])));
  }
  __syncthreads();
  if (t < DD) atomicMax(&scale_bits[t], smax[t]);
}

// K2: build padded prescaled pf[f][28] = {f*r (27), -0.5*||f*r||^2}, plus
// qp[q][28] = {q*r (27), 1.0} and qnorm.  Reads staged via LDS for coalescing.
__global__ __launch_bounds__(NTHR) void k_prepfn(
    const float* __restrict__ queries, const float* __restrict__ feats,
    const unsigned* __restrict__ scale_bits, float* __restrict__ qp,
    float* __restrict__ qnorm, float* __restrict__ pf, int nfeat) {
  __shared__ float rs[DD];
  __shared__ float rows[NTHR*DD];            // 27648 B
  int t = threadIdx.x;
  if (t < DD) {
    float s = __uint_as_float(scale_bits[t]);
    rs[t] = (s == 0.f) ? 0.f : 1.f / s;
  }
  __syncthreads();
  int fbase = blockIdx.x * NTHR;
  int gbase = fbase * DD;
  int ntot  = nfeat * DD;
  #pragma unroll
  for (int j = 0; j < DD; ++j) {             // coalesced: stride NTHR
    int idx = t + j*NTHR;
    int g = gbase + idx;
    rows[idx] = (g < ntot) ? feats[g] : 0.f;
  }
  __syncthreads();
  int f = fbase + t;
  if (f < nfeat) {
    float* dst = pf + (size_t)f * DP;
    float acc = 0.f;
    #pragma unroll
    for (int d = 0; d < DD; ++d) {
      float x = rows[t*DD + d] * rs[d];
      dst[d] = x;
      acc = fmaf(x, x, acc);
    }
    dst[DD] = -0.5f * acc;
  }
  if (blockIdx.x == 0) {
    for (int qq = t; qq < NQ; qq += NTHR) {
      float nrm = 0.f;
      #pragma unroll
      for (int d = 0; d < DD; ++d) {
        float v = queries[qq*DD + d] * rs[d];   // q*r (reference rounding)
        qp[qq*DP + d] = v;
        nrm = fmaf(v, v, nrm);
      }
      qp[qq*DP + DD] = 1.0f;                    // folds the -0.5||f||^2 term
      qnorm[qq] = nrm;
    }
  }
}

// insert acc into descending top-3 (largest acc == smallest d2); strict > keeps earliest idx
#define TINS(acc, fi) do {                                                \
    if ((acc) > s2) {                                                     \
      if ((acc) > s0)      { s2=s1;i2=i1; s1=s0;i1=i0; s0=(acc);i0=(fi); }\
      else if ((acc) > s1) { s2=s1;i2=i1; s1=(acc);i1=(fi); }             \
      else                 { s2=(acc); i2=(fi); }                         \
    }                                                                     \
  } while (0)

#define FDOT(rv, qv) do {                    \
    a = fmaf((rv).x, (qv).x, a);             \
    a = fmaf((rv).y, (qv).y, a);             \
    a = fmaf((rv).z, (qv).z, a);             \
    a = fmaf((rv).w, (qv).w, a);             \
  } while (0)

// K3: per-wave KNN, 1 query per lane.  Block b: query group qg=b/NSLICE
// (64 queries), feature slice b%NSLICE split across 4 waves.  Hot loop:
// 7 x dwordx4 (padded prescaled row, 16B-aligned) + 28 FMA per feature.
// acc = sum_d fs_d*qs_d - 0.5*||fs||^2;  d2 = -2*acc + qnorm (at merge).
// Working set ~ 28(q)+28(row)+8 regs -> fits default allocation, no remat fight.
__global__ __launch_bounds__(NTHR) void k_knn(
    const float4* __restrict__ pf4, const float4* __restrict__ qp4,
    float* __restrict__ pd2v, int* __restrict__ pd2i, int nfeat) {
  int t = threadIdx.x;
  int lane = t & 63;
  int w = t >> 6;
  int b = blockIdx.x;
  int qg    = b >> 8;                        // b / NSLICE (NSLICE=256)
  int slice = b & (NSLICE-1);

  int myq = qg*64 + lane;
  const float4* qb = qp4 + (size_t)myq * 7;
  float4 q0 = qb[0], q1 = qb[1], q2 = qb[2], q3 = qb[3],
         q4 = qb[4], q5 = qb[5], q6 = qb[6];

  float s0=-INFINITY, s1=-INFINITY, s2=-INFINITY;
  int   i0=0x7fffffff, i1=0x7fffffff, i2=0x7fffffff;

  int S = (nfeat + NSLICE - 1) / NSLICE;     // 782
  int base = slice * S;
  int cnt = nfeat - base; if (cnt > S) cnt = S; if (cnt < 0) cnt = 0;
  int fb = base + (cnt * w) / 4;
  int fe = base + (cnt * (w+1)) / 4;

  for (int f = fb; f < fe; ++f) {
    const float4* r = pf4 + (size_t)f * 7;   // row = 7 aligned float4
    float4 r0 = r[0], r1 = r[1], r2 = r[2], r3 = r[3],
           r4 = r[4], r5 = r[5], r6 = r[6];
    float a = 0.f;
    FDOT(r0, q0); FDOT(r1, q1); FDOT(r2, q2); FDOT(r3, q3);
    FDOT(r4, q4); FDOT(r5, q5); FDOT(r6, q6);   // includes -0.5||f||^2 * 1.0
    TINS(a, f);
  }

  // intra-block merge: 4 waves x 64 query-slots x top3 -> block top3 per query
  __shared__ float sv[4][64][3];
  __shared__ int   sx[4][64][3];
  sv[w][lane][0] = s0; sv[w][lane][1] = s1; sv[w][lane][2] = s2;
  sx[w][lane][0] = i0; sx[w][lane][1] = i1; sx[w][lane][2] = i2;
  __syncthreads();
  if (t < 64) {
    float b0=-INFINITY, b1=-INFINITY, b2=-INFINITY;
    int   x0=0x7fffffff, x1=0x7fffffff, x2=0x7fffffff;
    #pragma unroll
    for (int ww = 0; ww < 4; ++ww) {
      #pragma unroll
      for (int j = 0; j < 3; ++j) {
        float v = sv[ww][t][j]; int ix = sx[ww][t][j];
        if (v > b2 || (v == b2 && ix < x2)) {
          if (v > b0 || (v == b0 && ix < x0))      { b2=b1;x2=x1; b1=b0;x1=x0; b0=v;x0=ix; }
          else if (v > b1 || (v == b1 && ix < x1)) { b2=b1;x2=x1; b1=v;x1=ix; }
          else                                     { b2=v; x2=ix; }
        }
      }
    }
    int q = qg*64 + t;
    long o = (long)q * NCAND + slice*3;
    pd2v[o+0] = -2.f*b0; pd2v[o+1] = -2.f*b1; pd2v[o+2] = -2.f*b2;   // key = d2 - qnorm
    pd2i[o+0] = x0;      pd2i[o+1] = x1;      pd2i[o+2] = x2;
  }
}

// ascending insert into (c0<=c1<=c2), tie-break smaller index
#define INS(vv, ii) do { \
  if ((vv) < c2 || ((vv) == c2 && (ii) < j2)) { \
    if ((vv) < c0 || ((vv) == c0 && (ii) < j0))      { c2=c1;j2=j1; c1=c0;j1=j0; c0=(vv);j0=(ii); } \
    else if ((vv) < c1 || ((vv) == c1 && (ii) < j1)) { c2=c1;j2=j1; c1=(vv);j1=(ii); } \
    else                                             { c2=(vv); j2=(ii); } \
  } \
} while (0)

// K4: one block per query — merge NCAND coalesced candidates, then epilogue.
__global__ __launch_bounds__(NTHR) void k_merge(
    const float* __restrict__ pd2v, const int* __restrict__ pd2i,
    const float* __restrict__ qnorm, const float* __restrict__ labels,
    float* __restrict__ out) {
  __shared__ float sk[NTHR*3];
  __shared__ int   si[NTHR*3];
  int q = blockIdx.x, t = threadIdx.x;
  float c0=INFINITY, c1=INFINITY, c2=INFINITY;
  int   j0=0x7fffffff, j1=0x7fffffff, j2=0x7fffffff;
  const float* pv = pd2v + (long)q * NCAND;
  const int*   pi = pd2i + (long)q * NCAND;
  for (int i = t; i < NCAND; i += NTHR) {
    float v = pv[i]; int ix = pi[i];
    INS(v, ix);
  }
  sk[t*3+0]=c0; sk[t*3+1]=c1; sk[t*3+2]=c2;
  si[t*3+0]=j0; si[t*3+1]=j1; si[t*3+2]=j2;
  __syncthreads();
  if (t < 64) {
    for (int s = 1; s < 4; ++s) {
      int bb = t + s*64;
      #pragma unroll
      for (int k = 0; k < 3; ++k) { float v = sk[bb*3+k]; int ix = si[bb*3+k]; INS(v, ix); }
    }
    sk[t*3+0]=c0; sk[t*3+1]=c1; sk[t*3+2]=c2;
    si[t*3+0]=j0; si[t*3+1]=j1; si[t*3+2]=j2;
  }
  __syncthreads();
  if (t == 0) {
    for (int s = 1; s < 64; ++s) {
      #pragma unroll
      for (int k = 0; k < 3; ++k) { float v = sk[s*3+k]; int ix = si[s*3+k]; INS(v, ix); }
    }
    float qn = qnorm[q];
    float kd0 = sqrtf(fmaxf(c0 + qn, 0.f));
    float kd1 = sqrtf(fmaxf(c1 + qn, 0.f));
    float kd2 = sqrtf(fmaxf(c2 + qn, 0.f));
    const float* l0 = labels + (long)j0 * NC;
    const float* l1 = labels + (long)j1 * NC;
    const float* l2 = labels + (long)j2 * NC;
    float inv0 = 1.f / ((kd0 == 0.f) ? 1.f : kd0);
    float inv1 = 1.f / ((kd1 == 0.f) ? 1.f : kd1);
    float inv2 = 1.f / ((kd2 == 0.f) ? 1.f : kd2);
    float wv[NC];
    #pragma unroll
    for (int cc = 0; cc < NC; ++cc)
      wv[cc] = l0[cc]*inv0 + l1[cc]*inv1 + l2[cc]*inv2;
    int am = 0; float bw = wv[0];
    #pragma unroll
    for (int cc = 1; cc < NC; ++cc) if (wv[cc] > bw) { bw = wv[cc]; am = cc; }
    float* o = out + q * (KK + NC);
    o[0] = kd0; o[1] = kd1; o[2] = kd2;
    if (kd0 == 0.f) {
      #pragma unroll
      for (int cc = 0; cc < NC; ++cc) o[3+cc] = l0[cc];
    } else {
      #pragma unroll
      for (int cc = 0; cc < NC; ++cc) o[3+cc] = (cc == am) ? 1.f : 0.f;
    }
  }
}

extern "C" void kernel_launch(void* const* d_in, const int* in_sizes, int n_in,
                              void* d_out, int out_size, void* d_ws, size_t ws_size,
                              hipStream_t stream) {
  const float* queries = (const float*)d_in[0];   // (512, 27)
  const float* feats   = (const float*)d_in[1];   // (200000, 27)
  const float* labels  = (const float*)d_in[2];   // (200000, 10)
  float* out = (float*)d_out;                     // (512, 13)
  char*  ws  = (char*)d_ws;

  int total = in_sizes[1];                         // 5,400,000
  int nfeat = total / DD;                          // 200,000

  unsigned* scale_bits = (unsigned*)ws;            // 27 u32 @ 0 (zeroed)
  float* qnorm  = (float*)(ws + 512);              // 512 f32
  float* qp     = (float*)(ws + 4096);             // 512*28 f32 (57 KB, 16B-aligned)
  float* pd2v   = (float*)(ws + 65536);            // [512][768] f32 (1.57 MB)
  int*   pd2i   = (int*)(ws + 65536 + 1572864);    // [512][768] i32 (1.57 MB)
  float* pf     = (float*)(ws + 4194304);          // [200000][28] f32 (22.4 MB, 16B-aligned)

  hipMemsetAsync(ws, 0, 128, stream);              // zero scale_bits
  k_scale<<<864, 256, 0, stream>>>(feats, scale_bits, total, total / 4);
  k_prepfn<<<(nfeat + NTHR - 1) / NTHR, NTHR, 0, stream>>>(queries, feats, scale_bits,
                                                           qp, qnorm, pf, nfeat);
  k_knn  <<<NBLK, NTHR, 0, stream>>>((const float4*)pf, (const float4*)qp, pd2v, pd2i, nfeat);
  k_merge<<<NQ, NTHR, 0, stream>>>(pd2v, pd2i, qnorm, labels, out);
}

// Round 9
// 292.690 us; speedup vs baseline: 1.4820x; 1.4820x over previous
//
#include <hip/hip_runtime.h>
#include <math.h>

#define NQ     512
#define DD     27
#define NC     10
#define KK     3
#define NTHR   256
#define NSLICE 1024             // feature slices == blocks (4 blocks/CU resident)
#define NCAND  (NSLICE*3)       // 3072 candidates per query

static __device__ __forceinline__ unsigned fbits(float x){ return __float_as_uint(x); }

// K1: scale[d] = max |features[:,d]| (proven r2-r8).
__global__ void k_scale(const float* __restrict__ feats, unsigned* __restrict__ scale_bits,
                        int total, int total_f4) {
  __shared__ unsigned smax[DD];
  int t = threadIdx.x;
  if (t < DD) smax[t] = 0u;
  __syncthreads();
  int gid = blockIdx.x * blockDim.x + t;
  int stride = gridDim.x * blockDim.x;       // 864*256 = 221184 f4 ≡ 0 mod 27
  const float4* f4 = (const float4*)feats;
  float m0=0.f, m1=0.f, m2=0.f, m3=0.f;
  for (int i = gid; i < total_f4; i += stride) {
    float4 v = f4[i];
    m0 = fmaxf(m0, fabsf(v.x));
    m1 = fmaxf(m1, fabsf(v.y));
    m2 = fmaxf(m2, fabsf(v.z));
    m3 = fmaxf(m3, fabsf(v.w));
  }
  int d0 = (4*gid) % DD;
  atomicMax(&smax[d0],          fbits(m0));
  atomicMax(&smax[(d0+1)%DD],   fbits(m1));
  atomicMax(&smax[(d0+2)%DD],   fbits(m2));
  atomicMax(&smax[(d0+3)%DD],   fbits(m3));
  if (gid == 0) {
    for (int i = total_f4*4; i < total; ++i)
      atomicMax(&scale_bits[i % DD], fbits(fabsf(feats[i])));
  }
  __syncthreads();
  if (t < DD) atomicMax(&scale_bits[t], smax[t]);
}

// K2: qp = q*r^2 (scale folded into query side, proven r3-r8); qnorm = sum((q*r)^2).
__global__ void k_prep(const float* __restrict__ queries, const unsigned* __restrict__ scale_bits,
                       float* __restrict__ qp, float* __restrict__ qnorm) {
  __shared__ float rs[DD];
  int t = threadIdx.x;
  if (t < DD) {
    float s = __uint_as_float(scale_bits[t]);
    rs[t] = (s == 0.f) ? 0.f : 1.f / s;
  }
  __syncthreads();
  float nrm = 0.f;
  #pragma unroll
  for (int d = 0; d < DD; ++d) {
    float v = queries[t*DD + d] * rs[d];    // q*r (reference rounding)
    qp[t*DD + d] = v * rs[d];               // q*r^2
    nrm = fmaf(v, v, nrm);
  }
  qnorm[t] = nrm;
}

// K2b: fnorm2[f] = sum_d (f_d * r_d)^2 (rows LDS-staged for coalescing, r7 pattern).
__global__ __launch_bounds__(NTHR) void k_fnorm(
    const float* __restrict__ feats, const unsigned* __restrict__ scale_bits,
    float* __restrict__ fnorm2, int nfeat) {
  __shared__ float rs[DD];
  __shared__ float rows[NTHR*DD];
  int t = threadIdx.x;
  if (t < DD) {
    float s = __uint_as_float(scale_bits[t]);
    rs[t] = (s == 0.f) ? 0.f : 1.f / s;
  }
  __syncthreads();
  int fbase = blockIdx.x * NTHR;
  int gbase = fbase * DD;
  int ntot  = nfeat * DD;
  #pragma unroll
  for (int j = 0; j < DD; ++j) {
    int idx = t + j*NTHR;
    int g = gbase + idx;
    rows[idx] = (g < ntot) ? feats[g] : 0.f;
  }
  __syncthreads();
  int f = fbase + t;
  if (f < nfeat) {
    float acc = 0.f;
    #pragma unroll
    for (int d = 0; d < DD; ++d) { float v = rows[t*DD + d] * rs[d]; acc = fmaf(v, v, acc); }
    fnorm2[f] = acc;
  }
}

// insert acc into descending top-3 (largest acc == smallest d2); strict > keeps earliest idx
#define TINS(acc, fi, s0, s1, s2, i0, i1, i2) do {                        \
    if ((acc) > s2) {                                                     \
      if ((acc) > s0)      { s2=s1;i2=i1; s1=s0;i1=i0; s0=(acc);i0=(fi); }\
      else if ((acc) > s1) { s2=s1;i2=i1; s1=(acc);i1=(fi); }             \
      else                 { s2=(acc); i2=(fi); }                         \
    }                                                                     \
  } while (0)

#define DECLQ(d)  float q0_##d = qp[q0i*DD + (d)]; float q1_##d = qp[q1i*DD + (d)];
#define QF(d)     { float fv_ = row[d]; a0 = fmaf(fv_, q0_##d, a0); a1 = fmaf(fv_, q1_##d, a1); }

// K3: per-wave KNN.  Block = one feature slice (196 rows); its 4 waves each own
// a different query quarter (2 q/lane) and ALL iterate the same rows -> the
// feature row (wave-uniform address) is s_loaded to SGPRs and shared via the
// scalar cache across waves.  Hot loop: ~29 SMEM + 54 v_fma(sgpr,vgpr,vgpr).
// KEY FIX vs r4-r8: __syncthreads() between the query-register prologue and the
// hot loop.  A barrier is a scheduling fence -> the 54 query loads CANNOT be
// sunk into the loop (r2, the only round where queries stayed resident
// [VGPR=84], had exactly this barrier; r4-r8 [VGPR 32-52, reload storm] did not).
__global__ __launch_bounds__(NTHR) void k_knn(
    const float* __restrict__ feats, const float* __restrict__ qp,
    const float* __restrict__ fnorm2, float* __restrict__ pd2v,
    int* __restrict__ pd2i, int nfeat) {
  int t = threadIdx.x;
  int lane = t & 63;
  int w = t >> 6;                            // query quarter (0..3)
  int slice = blockIdx.x;

  int q0i = w*128 + lane;
  int q1i = q0i + 64;
  DECLQ(0)  DECLQ(1)  DECLQ(2)  DECLQ(3)  DECLQ(4)  DECLQ(5)  DECLQ(6)
  DECLQ(7)  DECLQ(8)  DECLQ(9)  DECLQ(10) DECLQ(11) DECLQ(12) DECLQ(13)
  DECLQ(14) DECLQ(15) DECLQ(16) DECLQ(17) DECLQ(18) DECLQ(19) DECLQ(20)
  DECLQ(21) DECLQ(22) DECLQ(23) DECLQ(24) DECLQ(25) DECLQ(26)
  asm volatile("" : "+v"(q0_0),"+v"(q0_1),"+v"(q0_2),"+v"(q0_3),"+v"(q0_4),
                    "+v"(q0_5),"+v"(q0_6),"+v"(q0_7),"+v"(q0_8),"+v"(q0_9),
                    "+v"(q0_10),"+v"(q0_11),"+v"(q0_12),"+v"(q0_13));
  asm volatile("" : "+v"(q0_14),"+v"(q0_15),"+v"(q0_16),"+v"(q0_17),"+v"(q0_18),
                    "+v"(q0_19),"+v"(q0_20),"+v"(q0_21),"+v"(q0_22),"+v"(q0_23),
                    "+v"(q0_24),"+v"(q0_25),"+v"(q0_26));
  asm volatile("" : "+v"(q1_0),"+v"(q1_1),"+v"(q1_2),"+v"(q1_3),"+v"(q1_4),
                    "+v"(q1_5),"+v"(q1_6),"+v"(q1_7),"+v"(q1_8),"+v"(q1_9),
                    "+v"(q1_10),"+v"(q1_11),"+v"(q1_12),"+v"(q1_13));
  asm volatile("" : "+v"(q1_14),"+v"(q1_15),"+v"(q1_16),"+v"(q1_17),"+v"(q1_18),
                    "+v"(q1_19),"+v"(q1_20),"+v"(q1_21),"+v"(q1_22),"+v"(q1_23),
                    "+v"(q1_24),"+v"(q1_25),"+v"(q1_26));

  __syncthreads();   // <-- the fence: query loads cannot sink past this

  float s00=-INFINITY, s01=-INFINITY, s02=-INFINITY;
  float s10=-INFINITY, s11=-INFINITY, s12=-INFINITY;
  int   i00=0x7fffffff, i01=0x7fffffff, i02=0x7fffffff;
  int   i10=0x7fffffff, i11=0x7fffffff, i12=0x7fffffff;

  int S = (nfeat + NSLICE - 1) / NSLICE;     // 196
  int base = slice * S;
  int cnt = nfeat - base; if (cnt > S) cnt = S; if (cnt < 0) cnt = 0;
  int fe = base + cnt;

  for (int f = base; f < fe; ++f) {
    const float* row = feats + (size_t)f * DD;   // wave-uniform -> s_load
    float fn = fnorm2[f];                        // wave-uniform -> s_load
    float a0 = -0.5f * fn;
    float a1 = -0.5f * fn;
    QF(0)  QF(1)  QF(2)  QF(3)  QF(4)  QF(5)  QF(6)  QF(7)  QF(8)
    QF(9)  QF(10) QF(11) QF(12) QF(13) QF(14) QF(15) QF(16) QF(17)
    QF(18) QF(19) QF(20) QF(21) QF(22) QF(23) QF(24) QF(25) QF(26)
    TINS(a0, f, s00, s01, s02, i00, i01, i02);
    TINS(a1, f, s10, s11, s12, i10, i11, i12);
  }

  // wave owns its 128 queries exclusively -> direct partial write, no merge.
  // layout [q][NCAND]: coalesced k_merge reads; key = -2*acc = d2 - qnorm
  long o0 = (long)q0i * NCAND + slice*3;
  pd2v[o0+0] = -2.f*s00; pd2v[o0+1] = -2.f*s01; pd2v[o0+2] = -2.f*s02;
  pd2i[o0+0] = i00;      pd2i[o0+1] = i01;      pd2i[o0+2] = i02;
  long o1 = (long)q1i * NCAND + slice*3;
  pd2v[o1+0] = -2.f*s10; pd2v[o1+1] = -2.f*s11; pd2v[o1+2] = -2.f*s12;
  pd2i[o1+0] = i10;      pd2i[o1+1] = i11;      pd2i[o1+2] = i12;
}

// ascending insert into (c0<=c1<=c2), tie-break smaller index
#define INS(vv, ii) do { \
  if ((vv) < c2 || ((vv) == c2 && (ii) < j2)) { \
    if ((vv) < c0 || ((vv) == c0 && (ii) < j0))      { c2=c1;j2=j1; c1=c0;j1=j0; c0=(vv);j0=(ii); } \
    else if ((vv) < c1 || ((vv) == c1 && (ii) < j1)) { c2=c1;j2=j1; c1=(vv);j1=(ii); } \
    else                                             { c2=(vv); j2=(ii); } \
  } \
} while (0)

// K4: one block per query — merge NCAND coalesced candidates, then epilogue.
__global__ __launch_bounds__(NTHR) void k_merge(
    const float* __restrict__ pd2v, const int* __restrict__ pd2i,
    const float* __restrict__ qnorm, const float* __restrict__ labels,
    float* __restrict__ out) {
  __shared__ float sk[NTHR*3];
  __shared__ int   si[NTHR*3];
  int q = blockIdx.x, t = threadIdx.x;
  float c0=INFINITY, c1=INFINITY, c2=INFINITY;
  int   j0=0x7fffffff, j1=0x7fffffff, j2=0x7fffffff;
  const float* pv = pd2v + (long)q * NCAND;
  const int*   pi = pd2i + (long)q * NCAND;
  for (int i = t; i < NCAND; i += NTHR) {
    float v = pv[i]; int ix = pi[i];
    INS(v, ix);
  }
  sk[t*3+0]=c0; sk[t*3+1]=c1; sk[t*3+2]=c2;
  si[t*3+0]=j0; si[t*3+1]=j1; si[t*3+2]=j2;
  __syncthreads();
  if (t < 64) {
    for (int s = 1; s < 4; ++s) {
      int bb = t + s*64;
      #pragma unroll
      for (int k = 0; k < 3; ++k) { float v = sk[bb*3+k]; int ix = si[bb*3+k]; INS(v, ix); }
    }
    sk[t*3+0]=c0; sk[t*3+1]=c1; sk[t*3+2]=c2;
    si[t*3+0]=j0; si[t*3+1]=j1; si[t*3+2]=j2;
  }
  __syncthreads();
  if (t == 0) {
    for (int s = 1; s < 64; ++s) {
      #pragma unroll
      for (int k = 0; k < 3; ++k) { float v = sk[s*3+k]; int ix = si[s*3+k]; INS(v, ix); }
    }
    float qn = qnorm[q];
    float kd0 = sqrtf(fmaxf(c0 + qn, 0.f));
    float kd1 = sqrtf(fmaxf(c1 + qn, 0.f));
    float kd2 = sqrtf(fmaxf(c2 + qn, 0.f));
    const float* l0 = labels + (long)j0 * NC;
    const float* l1 = labels + (long)j1 * NC;
    const float* l2 = labels + (long)j2 * NC;
    float inv0 = 1.f / ((kd0 == 0.f) ? 1.f : kd0);
    float inv1 = 1.f / ((kd1 == 0.f) ? 1.f : kd1);
    float inv2 = 1.f / ((kd2 == 0.f) ? 1.f : kd2);
    float wv[NC];
    #pragma unroll
    for (int cc = 0; cc < NC; ++cc)
      wv[cc] = l0[cc]*inv0 + l1[cc]*inv1 + l2[cc]*inv2;
    int am = 0; float bw = wv[0];
    #pragma unroll
    for (int cc = 1; cc < NC; ++cc) if (wv[cc] > bw) { bw = wv[cc]; am = cc; }
    float* o = out + q * (KK + NC);
    o[0] = kd0; o[1] = kd1; o[2] = kd2;
    if (kd0 == 0.f) {
      #pragma unroll
      for (int cc = 0; cc < NC; ++cc) o[3+cc] = l0[cc];
    } else {
      #pragma unroll
      for (int cc = 0; cc < NC; ++cc) o[3+cc] = (cc == am) ? 1.f : 0.f;
    }
  }
}

extern "C" void kernel_launch(void* const* d_in, const int* in_sizes, int n_in,
                              void* d_out, int out_size, void* d_ws, size_t ws_size,
                              hipStream_t stream) {
  const float* queries = (const float*)d_in[0];   // (512, 27)
  const float* feats   = (const float*)d_in[1];   // (200000, 27)
  const float* labels  = (const float*)d_in[2];   // (200000, 10)
  float* out = (float*)d_out;                     // (512, 13)
  char*  ws  = (char*)d_ws;

  int total = in_sizes[1];                         // 5,400,000
  int nfeat = total / DD;                          // 200,000

  unsigned* scale_bits = (unsigned*)ws;            // 27 u32 @ 0 (zeroed)
  float* qnorm  = (float*)(ws + 512);              // 512 f32
  float* qp     = (float*)(ws + 4096);             // 512*27 f32
  float* fnorm2 = (float*)(ws + 65536);            // 200000 f32 (800 KB)
  float* pd2v   = (float*)(ws + 1048576);          // [512][3072] f32 (6.29 MB)
  int*   pd2i   = (int*)(ws + 8388608);            // [512][3072] i32 (6.29 MB) -> ends 14.7 MB

  hipMemsetAsync(ws, 0, 128, stream);              // zero scale_bits
  k_scale<<<864, 256, 0, stream>>>(feats, scale_bits, total, total / 4);
  k_prep <<<1, NQ, 0, stream>>>(queries, scale_bits, qp, qnorm);
  k_fnorm<<<(nfeat + NTHR - 1) / NTHR, NTHR, 0, stream>>>(feats, scale_bits, fnorm2, nfeat);
  k_knn  <<<NSLICE, NTHR, 0, stream>>>(feats, qp, fnorm2, pd2v, pd2i, nfeat);
  k_merge<<<NQ, NTHR, 0, stream>>>(pd2v, pd2i, qnorm, labels, out);
}